// Round 6
// baseline (138.938 us; speedup 1.0000x reference)
//
#include <hip/hip_runtime.h>
#include <hip/hip_bf16.h>
#include <stdint.h>

#define LL 2048
#define SS 2048
#define HH 8
#define EE 64
#define RSG 512   // global row stride in elements (H*E)

typedef float v4f  __attribute__((ext_vector_type(4)));
typedef float v16f __attribute__((ext_vector_type(16)));
typedef short s4v  __attribute__((ext_vector_type(4)));
typedef short s8v  __attribute__((ext_vector_type(8)));

// fp32 -> bf16 bits, round-to-nearest-even
__device__ __forceinline__ short f2bf(float f) {
    unsigned u = __float_as_uint(f);
    u = (u + 0x7fffu + ((u >> 16) & 1u)) >> 16;
    return (short)u;
}

__device__ __forceinline__ s4v pack4bf(float a, float b, float c, float d) {
    float2 ab = make_float2(a, b), cd = make_float2(c, d);
    __hip_bfloat162 r0 = __float22bfloat162_rn(ab);
    __hip_bfloat162 r1 = __float22bfloat162_rn(cd);
    s4v r;
    __builtin_memcpy(&r, &r0, 4);
    __builtin_memcpy(((char*)&r) + 4, &r1, 4);
    return r;
}

// ---------------- prepass (identical to round 4, verified) ----------------
// K: fp32 -> bf16, natural layout.
// Vimg per (b,h,64-row tile): rows e=0..63, each row 8 chunks of 16B.
// Chunk at position pos holds logical chunk c = pos ^ (e&7).
// Logical slot u = 8c + j holds V[s][e] with s = 16*(c>>1)+4*(c&1)+8*(j>>2)+(j&3).
__global__ __launch_bounds__(256)
void dsattn_prep(const float* __restrict__ kk, const float* __restrict__ vv,
                 short* __restrict__ kbf, short* __restrict__ vimg)
{
    __shared__ float T[64][68];
    const int t = threadIdx.x;
    const int blk = blockIdx.x;
    if (blk < 1024) {
        const float* src = kk + (size_t)blk * 4096;
        short* dst = kbf + (size_t)blk * 4096;
        #pragma unroll
        for (int c = 0; c < 4; ++c) {
            v4f d = *(const v4f*)(src + (c * 256 + t) * 4);
            *(s4v*)(dst + (c * 256 + t) * 4) = pack4bf(d[0], d[1], d[2], d[3]);
        }
    } else {
        const int vb = blk - 1024;           // (b*8 + h)*32 + ts
        const int b = vb >> 8, h = (vb >> 5) & 7, ts = vb & 31;
        const float* vp = vv + ((size_t)b * SS + ts * 64) * RSG + h * EE;
        #pragma unroll
        for (int c = 0; c < 4; ++c) {
            int idx = c * 256 + t, s = idx >> 4, e0 = (idx & 15) << 2;
            *(v4f*)&T[s][e0] = *(const v4f*)(vp + (size_t)s * RSG + e0);
        }
        __syncthreads();
        short* dst = vimg + (size_t)vb * 4096;
        #pragma unroll
        for (int half = 0; half < 2; ++half) {
            int ci = half * 256 + t;         // 16B chunk index 0..511
            int e = ci >> 3, pos = ci & 7;
            int c = pos ^ (e & 7);
            int sbase = 16 * (c >> 1) + 4 * (c & 1);
            s8v ov;
            #pragma unroll
            for (int j = 0; j < 8; ++j) {
                int s = sbase + 8 * (j >> 2) + (j & 3);
                ov[j] = f2bf(T[s][e]);
            }
            *(s8v*)(dst + ci * 8) = ov;
        }
    }
}

// ---------------- main: 128 Q rows/block, 4-buffer depth-2 pipeline,
// cross-tile QK(t) / PV(t-1) software pipelining.
__global__ __launch_bounds__(256, 2)
void dsattn_main(const float* __restrict__ q, const short* __restrict__ kbf,
                 const short* __restrict__ vimg, const float* __restrict__ tau,
                 float* __restrict__ out)
{
    __shared__ short KV[4][8192];   // 64 KB: per buf [0..4095] K tile, [4096..8191] V image

    const int t    = threadIdx.x;
    const int lane = t & 63;
    const int w    = t >> 6;
    const int l31  = lane & 31;
    const int hi   = lane >> 5;
    const int mt = blockIdx.x, h = blockIdx.y, b = blockIdx.z;

    const float scf = 0.125f * 1.44269504088896f * tau[b];  // tau*scale*log2e folded into Q

    // ---- Q B-frags: lane holds Q[w*32+l31][e = 16ks + 8hi + j], pre-scaled ----
    s8v qf[4];
    {
        const float* qb = q + ((size_t)b * LL + (size_t)mt * 128 + w * 32 + l31) * RSG
                            + h * EE + 8 * hi;
        #pragma unroll
        for (int ks = 0; ks < 4; ++ks) {
            v4f a0 = *(const v4f*)(qb + 16 * ks);
            v4f a1 = *(const v4f*)(qb + 16 * ks + 4);
            s4v p0 = pack4bf(a0[0] * scf, a0[1] * scf, a0[2] * scf, a0[3] * scf);
            s4v p1 = pack4bf(a1[0] * scf, a1[1] * scf, a1[2] * scf, a1[3] * scf);
            s8v f;
            #pragma unroll
            for (int j = 0; j < 4; ++j) { f[j] = p0[j]; f[4 + j] = p1[j]; }
            qf[ks] = f;
        }
    }

    // ---- staging source pointers (waves 0,1: K with src-side swizzle; 2,3: V) ----
    const char* gsrc;
    int jstr, tstr;
    if (w < 2) {
        int i = w * 256 + lane;
        int row = i >> 3;
        int c = (i & 7) ^ (row & 7);
        gsrc = (const char*)(kbf + (size_t)b * (SS * RSG) + h * EE) + row * (RSG * 2) + c * 16;
        jstr = 8 * RSG * 2;
        tstr = 64 * RSG * 2;
    } else {
        int i2 = (w - 2) * 256 + lane;
        gsrc = (const char*)(vimg + (((size_t)b * HH + h) * 32) * 4096) + i2 * 16;
        jstr = 1024; tstr = 8192;
    }

    #define STAGE(p)                                                                      \
        {                                                                                 \
            _Pragma("unroll")                                                             \
            for (int j = 0; j < 4; ++j) {                                                 \
                __builtin_amdgcn_global_load_lds(                                         \
                    (const __attribute__((address_space(1))) unsigned*)(gsrc + j * jstr), \
                    (__attribute__((address_space(3))) unsigned*)&KV[p][w * 2048 + j * 512], \
                    16, 0, 0);                                                            \
            }                                                                             \
            gsrc += tstr;                                                                 \
        }

    v16f oacc[2];
    #pragma unroll
    for (int mb = 0; mb < 2; ++mb)
        #pragma unroll
        for (int r = 0; r < 16; ++r) oacc[mb][r] = 0.0f;
    float rsum = 0.0f;

    const int xo = l31 & 7;
    const int rbase = l31 * 64;
    int kpos[4];
    #pragma unroll
    for (int ks = 0; ks < 4; ++ks) kpos[ks] = (((hi + 2 * ks) & 7) ^ xo) * 8;

    s8v pf[4];   // P fragments of tile t-1, carried in registers across iterations

    // QK for tile tt (buf tt&3) -> st
    #define DO_QK(tt, st)                                                          \
        {                                                                          \
            const short* Kp = &KV[(tt) & 3][0];                                    \
            _Pragma("unroll")                                                      \
            for (int mb = 0; mb < 2; ++mb) {                                       \
                v16f z;                                                            \
                _Pragma("unroll")                                                  \
                for (int r = 0; r < 16; ++r) z[r] = 0.0f;                          \
                _Pragma("unroll")                                                  \
                for (int ks = 0; ks < 4; ++ks) {                                   \
                    s8v kf = *(const s8v*)&Kp[mb * 2048 + rbase + kpos[ks]];       \
                    z = __builtin_amdgcn_mfma_f32_32x32x16_bf16(kf, qf[ks], z, 0, 0, 0); \
                }                                                                  \
                st[mb] = z;                                                        \
            }                                                                      \
        }

    // PV for tile tt (buf tt&3), consuming pf
    #define DO_PV(tt)                                                              \
        {                                                                          \
            const short* Vp = &KV[(tt) & 3][4096];                                 \
            _Pragma("unroll")                                                      \
            for (int mb = 0; mb < 2; ++mb) {                                       \
                v16f acc = oacc[mb];                                               \
                _Pragma("unroll")                                                  \
                for (int ks = 0; ks < 4; ++ks) {                                   \
                    s8v vf = *(const s8v*)&Vp[mb * 2048 + rbase + kpos[ks]];       \
                    acc = __builtin_amdgcn_mfma_f32_32x32x16_bf16(vf, pf[ks], acc, 0, 0, 0); \
                }                                                                  \
                oacc[mb] = acc;                                                    \
            }                                                                      \
        }

    // exp2, row-sum, pack P frags of this tile into pf
    #define DO_EXP(st)                                                             \
        {                                                                          \
            _Pragma("unroll")                                                      \
            for (int mb = 0; mb < 2; ++mb)                                         \
                _Pragma("unroll")                                                  \
                for (int r = 0; r < 16; ++r)                                       \
                    st[mb][r] = __builtin_amdgcn_exp2f(st[mb][r]);                 \
            float s0 = 0.f, s1 = 0.f;                                              \
            _Pragma("unroll")                                                      \
            for (int r = 0; r < 16; ++r) { s0 += st[0][r]; s1 += st[1][r]; }       \
            rsum += s0 + s1;                                                       \
            _Pragma("unroll")                                                      \
            for (int tt2 = 0; tt2 < 4; ++tt2) {                                    \
                int o = 8 * (tt2 & 1);                                             \
                const v16f& sv = st[tt2 >> 1];                                     \
                s4v lo = pack4bf(sv[o + 0], sv[o + 1], sv[o + 2], sv[o + 3]);      \
                s4v hs = pack4bf(sv[o + 4], sv[o + 5], sv[o + 6], sv[o + 7]);      \
                s8v f;                                                             \
                _Pragma("unroll")                                                  \
                for (int j = 0; j < 4; ++j) { f[j] = lo[j]; f[4 + j] = hs[j]; }    \
                pf[tt2] = f;                                                       \
            }                                                                      \
        }

    #define WAITBAR(n)                                                             \
        asm volatile("s_waitcnt vmcnt(" #n ") lgkmcnt(0)" ::: "memory");           \
        asm volatile("s_barrier" ::: "memory");

    STAGE(0);            // tile 0 -> buf 0
    STAGE(1);            // tile 1 -> buf 1   (8 loads/thread outstanding)

    // ---- peeled iteration 0: QK(0), no PV ----
    {
        WAITBAR(4);                          // tile 0 landed; tile 1 in flight
        STAGE(2);
        v16f st[2];
        DO_QK(0, st);
        DO_EXP(st);
    }

    // ---- steady state: it = 1..29, branch-free body ----
    for (int it = 1; it < 30; ++it) {
        WAITBAR(4);                          // tile it landed; tile it+1 in flight
        STAGE((it + 2) & 3);                 // overwrites buf of tile it-2 (reads done)
        v16f st[2];
        DO_QK(it, st);                       // buf it&3
        DO_PV(it - 1);                       // buf (it-1)&3 — independent MFMA stream
        DO_EXP(st);
    }

    // ---- peeled iteration 30 (no STAGE) ----
    {
        WAITBAR(4);                          // tile 30 landed; tile 31 in flight
        v16f st[2];
        DO_QK(30, st);
        DO_PV(29);
        DO_EXP(st);
    }
    // ---- peeled iteration 31 (drain) ----
    {
        WAITBAR(0);                          // tile 31 landed
        v16f st[2];
        DO_QK(31, st);
        DO_PV(30);
        DO_EXP(st);
    }
    DO_PV(31);                               // final PV epilogue

    // ---- denominator and store O^T -> O ----
    rsum += __shfl_xor(rsum, 32);
    const float inv = 1.0f / rsum;
    float* ob = out + ((size_t)b * LL + (size_t)mt * 128 + w * 32 + l31) * RSG + h * EE;
    #pragma unroll
    for (int mb = 0; mb < 2; ++mb)
        #pragma unroll
        for (int rq = 0; rq < 4; ++rq) {
            int e0 = 32 * mb + 8 * rq + 4 * hi;      // C-layout row = (reg&3)+8*(reg>>2)+4*hi
            v4f o4 = { oacc[mb][4 * rq + 0] * inv, oacc[mb][4 * rq + 1] * inv,
                       oacc[mb][4 * rq + 2] * inv, oacc[mb][4 * rq + 3] * inv };
            *(v4f*)(ob + e0) = o4;
        }
}

extern "C" void kernel_launch(void* const* d_in, const int* in_sizes, int n_in,
                              void* d_out, int out_size, void* d_ws, size_t ws_size,
                              hipStream_t stream) {
    const float* q   = (const float*)d_in[0];
    const float* k   = (const float*)d_in[1];
    const float* v   = (const float*)d_in[2];
    // d_in[3] = attn_mask (unused); d_in[5] = delta (cancels exactly in softmax)
    const float* tau = (const float*)d_in[4];
    float* out = (float*)d_out;

    short* kbf  = (short*)d_ws;                   // 4*2048*512 bf16 = 8.39 MB
    short* vimg = kbf + (size_t)4 * SS * RSG;     // 8.39 MB

    dsattn_prep<<<dim3(2048), dim3(256), 0, stream>>>(k, v, kbf, vimg);
    dsattn_main<<<dim3(LL / 128, HH, 4), dim3(256), 0, stream>>>(q, kbf, vimg, tau, out);
}